// Round 1
// baseline (573.360 us; speedup 1.0000x reference)
//
#include <hip/hip_runtime.h>

#define HB 32
#define HT 256
#define HC 2048
#define HH 16
#define HD 128
#define HM (HB * HT)  // 8192

typedef __bf16 bf16x8 __attribute__((ext_vector_type(8)));
typedef float f32x4 __attribute__((ext_vector_type(4)));

__device__ __forceinline__ unsigned short f2bf(float f) {
  unsigned u = __float_as_uint(f);
  u += 0x7FFFu + ((u >> 16) & 1u);  // round-to-nearest-even
  return (unsigned short)(u >> 16);
}

// ---------------- fused fp32 -> bf16 convert (x + 4 weights) ----------------
__global__ __launch_bounds__(256) void cvt_all(
    const float* __restrict__ x, const float* __restrict__ wq, const float* __restrict__ wk,
    const float* __restrict__ wv, const float* __restrict__ wo,
    unsigned short* __restrict__ xb, unsigned short* __restrict__ wqb,
    unsigned short* __restrict__ wkb, unsigned short* __restrict__ wvb,
    unsigned short* __restrict__ wob) {
  size_t i = (size_t)blockIdx.x * 256 + threadIdx.x;
  const float* src;
  unsigned short* dst;
  size_t off;
  if (i < 4194304) {
    src = x; dst = xb; off = i;
  } else {
    size_t j = i - 4194304;
    int w = (int)(j >> 20);
    off = j & 1048575;
    src = (w == 0) ? wq : (w == 1) ? wk : (w == 2) ? wv : wo;
    dst = (w == 0) ? wqb : (w == 1) ? wkb : (w == 2) ? wvb : wob;
  }
  float4 v = ((const float4*)src)[off];
  ushort4 o;
  o.x = f2bf(v.x); o.y = f2bf(v.y); o.z = f2bf(v.z); o.w = f2bf(v.w);
  ((ushort4*)dst)[off] = o;
}

// ---------------- GEMM core: 256x256 tile, BK=32, 4-deep LDS ring ----------------
// 8 waves (2M x 4N), per-wave 128x64 output via 16x16x32 MFMA (8 m-frags x 4 n-frags).
// T3+T4: 3 tiles prefetched ahead with global_load_lds; s_waitcnt vmcnt(8) (never 0
// in the main loop) + raw s_barrier once per K-tile. T5: setprio around MFMA cluster.
// Swizzle slot^((row>>1)&3): 16-row fragment reads spread over all 8 bank-groups,
// 2-way residual (free per m136), vs 4-way with the old 32x32 fragments.
__device__ __forceinline__ void gl_lds16(const unsigned short* g, unsigned short* l) {
  __builtin_amdgcn_global_load_lds((const __attribute__((address_space(1))) void*)g,
                                   (__attribute__((address_space(3))) void*)l, 16, 0, 0);
}

// wave wn owns col-blocks {h*128 + s, +16, +64+s, +80} with s=32*(wn&1), h=wn>>1:
// frag pair (nf, nf+2) is (d, d+64) of one head -> RoPE pair stays in-lane.
__device__ __forceinline__ int nfcol(int wn, int nf) {
  return (wn >> 1) * 128 + (wn & 1) * 32 + (nf & 1) * 16 + (nf >> 1) * 64;
}

// Stage one 256x32 A-tile + 256x32 B-tile (32 KB) for K-tile kt. 4 loads/thread.
// LDS dest linear (chunk c at byte c*16); source column pre-swizzled (m173 pattern).
__device__ __forceinline__ void stage_tile(const unsigned short* __restrict__ A,
                                           const unsigned short* __restrict__ W,
                                           unsigned short* dA, unsigned short* dW,
                                           int kt, int tid) {
#pragma unroll
  for (int i = 0; i < 2; i++) {
    int c = i * 512 + tid;
    int row = c >> 2, slot = c & 3;
    int gc = slot ^ ((row >> 1) & 3);
    gl_lds16(A + (size_t)row * HC + kt * 32 + gc * 8, dA + c * 8);
  }
#pragma unroll
  for (int i = 0; i < 2; i++) {
    int c = i * 512 + tid;
    int row = c >> 2, slot = c & 3;
    int gc = slot ^ ((row >> 1) & 3);
    gl_lds16(W + (size_t)row * HC + kt * 32 + gc * 8, dW + c * 8);
  }
}

#define NTILES 64  // K=2048 / BK=32

__device__ __forceinline__ void gemm_core8(const unsigned short* __restrict__ A,
                                           const unsigned short* __restrict__ W,
                                           unsigned short* lsA, unsigned short* lsB,
                                           f32x4 acc[8][4], int tid) {
  const int lane = tid & 63;
  const int l16 = lane & 15, quad = lane >> 4;
  const int wave = tid >> 6;
  const int wm = wave >> 2, wn = wave & 3;

  // prologue: stage tiles 0..2; vmcnt(8) -> tile 0 landed, tiles 1-2 in flight
  stage_tile(A, W, lsA, lsB, 0, tid);
  stage_tile(A, W, lsA + 8192, lsB + 8192, 1, tid);
  stage_tile(A, W, lsA + 16384, lsB + 16384, 2, tid);
  asm volatile("s_waitcnt vmcnt(8)");
  __builtin_amdgcn_s_barrier();

  for (int t = 0; t < NTILES; ++t) {
    const int cur = t & 3;
    const unsigned short* cA = lsA + cur * 8192;
    const unsigned short* cB = lsB + cur * 8192;
    // issue stage for tile t+3 first (overwrites buffer last read in iter t-1;
    // safe: those ds_reads completed before that iter's lgkmcnt+barrier)
    if (t + 3 < NTILES) {
      const int nb = (t + 3) & 3;
      stage_tile(A, W, lsA + nb * 8192, lsB + nb * 8192, t + 3, tid);
    }
    bf16x8 af[8], bfr[4];
#pragma unroll
    for (int mf = 0; mf < 8; mf++) {
      int row = wm * 128 + mf * 16 + l16;
      int slot = quad ^ ((row >> 1) & 3);
      af[mf] = *(const bf16x8*)(cA + row * 32 + slot * 8);
    }
#pragma unroll
    for (int nf = 0; nf < 4; nf++) {
      int row = nfcol(wn, nf) + l16;
      int slot = quad ^ ((row >> 1) & 3);
      bfr[nf] = *(const bf16x8*)(cB + row * 32 + slot * 8);
    }
    __builtin_amdgcn_s_setprio(1);
#pragma unroll
    for (int mf = 0; mf < 8; mf++)
#pragma unroll
      for (int nf = 0; nf < 4; nf++)
        acc[mf][nf] = __builtin_amdgcn_mfma_f32_16x16x32_bf16(af[mf], bfr[nf], acc[mf][nf], 0, 0, 0);
    __builtin_amdgcn_s_setprio(0);
    // counted vmcnt: <=8 outstanding = tiles t+2,t+3 -> tile t+1 fully landed.
    // tail drains 8 -> 4 -> 0 so the last tiles are guaranteed without a deep queue.
    if (t < NTILES - 3) {
      asm volatile("s_waitcnt vmcnt(8)");
    } else if (t == NTILES - 3) {
      asm volatile("s_waitcnt vmcnt(4)");
    } else if (t == NTILES - 2) {
      asm volatile("s_waitcnt vmcnt(0)");
    }
    __builtin_amdgcn_s_barrier();
  }
}

// Output projection GEMM: fp32 out [M, 2048]; grid (32, 8)
__global__ __launch_bounds__(512, 2) void gemm_out(const unsigned short* __restrict__ A,
                                                   const unsigned short* __restrict__ W,
                                                   float* __restrict__ outp) {
  __shared__ __align__(16) unsigned short lsA[32768];
  __shared__ __align__(16) unsigned short lsB[32768];
  const int tid = threadIdx.x;
  const int lane = tid & 63, wave = tid >> 6;
  const int l16 = lane & 15, quad = lane >> 4;
  const int wm = wave >> 2, wn = wave & 3;
  const int bm = blockIdx.x, bn = blockIdx.y;

  f32x4 acc[8][4];
#pragma unroll
  for (int i = 0; i < 8; i++)
#pragma unroll
    for (int j = 0; j < 4; j++) acc[i][j] = f32x4{0.f, 0.f, 0.f, 0.f};

  gemm_core8(A + (size_t)bm * 256 * HC, W + (size_t)bn * 256 * HC, lsA, lsB, acc, tid);

#pragma unroll
  for (int mf = 0; mf < 8; mf++)
#pragma unroll
    for (int nf = 0; nf < 4; nf++) {
      const int n = bn * 256 + nfcol(wn, nf) + l16;
#pragma unroll
      for (int r = 0; r < 4; r++) {
        const int m = bm * 256 + wm * 128 + mf * 16 + quad * 4 + r;
        outp[(size_t)m * HC + n] = acc[mf][nf][r];
      }
    }
}

// Fused QKV GEMM: grid (32, 24); blockIdx.y>>3 selects {Q,K,V}.
// Q,K -> [B,H,T,D] with RoPE fused; V -> [B,H,D,T] via operand swap (coalesced).
__global__ __launch_bounds__(512, 2) void gemm_qkv(const unsigned short* __restrict__ A,
                                                   const unsigned short* __restrict__ W0,
                                                   const unsigned short* __restrict__ W1,
                                                   const unsigned short* __restrict__ W2,
                                                   unsigned short* __restrict__ Qo,
                                                   unsigned short* __restrict__ Ko,
                                                   unsigned short* __restrict__ Vto) {
  __shared__ __align__(16) unsigned short lsA[32768];
  __shared__ __align__(16) unsigned short lsB[32768];
  const int tid = threadIdx.x;
  const int lane = tid & 63, wave = tid >> 6;
  const int l16 = lane & 15, quad = lane >> 4;
  const int wm = wave >> 2, wn = wave & 3;
  const int bm = blockIdx.x;
  const int which = blockIdx.y >> 3;
  const int bn = blockIdx.y & 7;

  f32x4 acc[8][4];
#pragma unroll
  for (int i = 0; i < 8; i++)
#pragma unroll
    for (int j = 0; j < 4; j++) acc[i][j] = f32x4{0.f, 0.f, 0.f, 0.f};

  if (which < 2) {
    const unsigned short* W = (which == 0) ? W0 : W1;
    unsigned short* outp = (which == 0) ? Qo : Ko;
    gemm_core8(A + (size_t)bm * 256 * HC, W + (size_t)bn * 256 * HC, lsA, lsB, acc, tid);
    // wave covers head h = bn*2 + (wn>>1); frag pair (p, p+2) = (d, d+64) in-lane.
    const int h = bn * 2 + (wn >> 1);
#pragma unroll
    for (int p = 0; p < 2; p++) {
      const int d = (wn & 1) * 32 + p * 16 + l16;  // [0,64)
      const float invf = __expf((float)d * (-0.14391156831212787f));
#pragma unroll
      for (int mf = 0; mf < 8; mf++)
#pragma unroll
        for (int r = 0; r < 4; r++) {
          const int m = bm * 256 + wm * 128 + mf * 16 + quad * 4 + r;
          const int t = m & 255, b = m >> 8;
          float ang = (float)t * invf;
          float sn, cs;
          __sincosf(ang, &sn, &cs);
          float lo = acc[mf][p][r], hi = acc[mf][p + 2][r];
          size_t base = (((size_t)b * HH + h) * HT + t) * HD;
          outp[base + d] = f2bf(lo * cs - hi * sn);
          outp[base + 64 + d] = f2bf(hi * cs + lo * sn);
        }
    }
  } else {
    // V^T: A-operand = wv channel tile (256 ch = 2 heads), B-operand = x token tile (256 = 1 batch).
    const int tok = bm;  // 0..31
    const int ch = bn;   // 0..7
    gemm_core8(W2 + (size_t)ch * 256 * HC, A + (size_t)tok * 256 * HC, lsA, lsB, acc, tid);
#pragma unroll
    for (int mf = 0; mf < 8; mf++)
#pragma unroll
      for (int nf = 0; nf < 4; nf++) {
        const int tcol = nfcol(wn, nf) + l16;
#pragma unroll
        for (int r = 0; r < 4; r++) {
          const int cabs = ch * 256 + wm * 128 + mf * 16 + quad * 4 + r;
          const int hh = cabs >> 7, d = cabs & 127;
          Vto[(((size_t)tok * HH + hh) * HD + d) * HT + tcol] = f2bf(acc[mf][nf][r]);
        }
      }
  }
}

// ---------------- causal flash attention ----------------
// Block = 4 waves; block handles 64 q-rows of one (b,h); wave owns 16 q-rows.
// Q,K in [B,H,T,D] (pre-RoPEd), Vt in [B,H,D,T]. Y written as [B,T,C] bf16.
__global__ __launch_bounds__(256) void attn_kernel(const unsigned short* __restrict__ Q,
                                                   const unsigned short* __restrict__ K,
                                                   const unsigned short* __restrict__ Vt,
                                                   unsigned short* __restrict__ Y) {
  const int g = blockIdx.x;
  const int wq = 3 - (g >> 9);
  const int bh = g & 511;
  const int wave = threadIdx.x >> 6;
  const int lane = threadIdx.x & 63;
  const int quad = lane >> 4, l16 = lane & 15;

  const unsigned short* Qh = Q + (size_t)bh * HT * HD;
  const unsigned short* Kh = K + (size_t)bh * HT * HD;
  const unsigned short* Vh = Vt + (size_t)bh * HD * HT;

  __shared__ __align__(16) unsigned short P[4][16 * 72];
  unsigned short* Pw = P[wave];

  const int qrow = wq * 64 + wave * 16;

  bf16x8 qf[4];
#pragma unroll
  for (int ks = 0; ks < 4; ks++)
    qf[ks] = *(const bf16x8*)(Qh + (size_t)(qrow + l16) * HD + ks * 32 + quad * 8);

  f32x4 o[8];
#pragma unroll
  for (int di = 0; di < 8; di++) o[di] = f32x4{0.f, 0.f, 0.f, 0.f};
  float mrow[4], lrow[4];
#pragma unroll
  for (int r = 0; r < 4; r++) { mrow[r] = -1e30f; lrow[r] = 0.f; }

  const float scale = 0.088388347648318447f;  // 1/sqrt(128)

  for (int ct = 0; ct <= wq; ++ct) {
    f32x4 s[4];
#pragma unroll
    for (int ni = 0; ni < 4; ni++) s[ni] = f32x4{0.f, 0.f, 0.f, 0.f};
    const int nimax = (ct == wq) ? wave : 3;
#pragma unroll
    for (int ks = 0; ks < 4; ks++) {
#pragma unroll
      for (int ni = 0; ni < 4; ni++) {
        if (ni <= nimax) {
          bf16x8 kf = *(const bf16x8*)(Kh + (size_t)(ct * 64 + ni * 16 + l16) * HD + ks * 32 + quad * 8);
          s[ni] = __builtin_amdgcn_mfma_f32_16x16x32_bf16(qf[ks], kf, s[ni], 0, 0, 0);
        }
      }
    }
    if (ct == wq) {
#pragma unroll
      for (int ni = 0; ni < 4; ni++)
#pragma unroll
        for (int r = 0; r < 4; r++) {
          int qr = wave * 16 + quad * 4 + r;
          int kc = ni * 16 + l16;
          s[ni][r] = (kc <= qr) ? s[ni][r] * scale : -1e30f;
        }
    } else {
#pragma unroll
      for (int ni = 0; ni < 4; ni++)
#pragma unroll
        for (int r = 0; r < 4; r++) s[ni][r] *= scale;
    }
#pragma unroll
    for (int r = 0; r < 4; r++) {
      float v = fmaxf(fmaxf(s[0][r], s[1][r]), fmaxf(s[2][r], s[3][r]));
      v = fmaxf(v, __shfl_xor(v, 1, 64));
      v = fmaxf(v, __shfl_xor(v, 2, 64));
      v = fmaxf(v, __shfl_xor(v, 4, 64));
      v = fmaxf(v, __shfl_xor(v, 8, 64));
      float mnew = fmaxf(mrow[r], v);
      float alpha = __expf(mrow[r] - mnew);
      mrow[r] = mnew;
      float rs = 0.f;
#pragma unroll
      for (int ni = 0; ni < 4; ni++) {
        float e = __expf(s[ni][r] - mnew);
        s[ni][r] = e;
        rs += e;
      }
      rs += __shfl_xor(rs, 1, 64);
      rs += __shfl_xor(rs, 2, 64);
      rs += __shfl_xor(rs, 4, 64);
      rs += __shfl_xor(rs, 8, 64);
      lrow[r] = lrow[r] * alpha + rs;
#pragma unroll
      for (int di = 0; di < 8; di++) o[di][r] *= alpha;
    }
#pragma unroll
    for (int ni = 0; ni < 4; ni++)
#pragma unroll
      for (int r = 0; r < 4; r++)
        Pw[(quad * 4 + r) * 72 + ni * 16 + l16] = f2bf(s[ni][r]);
#pragma unroll
    for (int ks = 0; ks < 2; ks++) {
      bf16x8 pf = *(const bf16x8*)(Pw + (size_t)l16 * 72 + ks * 32 + quad * 8);
#pragma unroll
      for (int di = 0; di < 8; di++) {
        bf16x8 vf = *(const bf16x8*)(Vh + (size_t)(di * 16 + l16) * HT + ct * 64 + ks * 32 + quad * 8);
        o[di] = __builtin_amdgcn_mfma_f32_16x16x32_bf16(pf, vf, o[di], 0, 0, 0);
      }
    }
  }

  const int b = bh >> 4, h = bh & 15;
#pragma unroll
  for (int r = 0; r < 4; r++) {
    float inv = 1.f / lrow[r];
    int t = qrow + quad * 4 + r;
    size_t rowb = ((size_t)b * HT + t) * HC + h * HD;
#pragma unroll
    for (int di = 0; di < 8; di++)
      Y[rowb + di * 16 + l16] = f2bf(o[di][r] * inv);
  }
}

// ---------------- launch ----------------
extern "C" void kernel_launch(void* const* d_in, const int* in_sizes, int n_in,
                              void* d_out, int out_size, void* d_ws, size_t ws_size,
                              hipStream_t stream) {
  const float* x  = (const float*)d_in[0];
  const float* wq = (const float*)d_in[1];
  const float* wk = (const float*)d_in[2];
  const float* wv = (const float*)d_in[3];
  const float* wo = (const float*)d_in[4];
  float* out = (float*)d_out;

  char* ws = (char*)d_ws;
  const size_t MB = (size_t)1 << 20;
  unsigned short* wqb = (unsigned short*)(ws + 0 * MB);
  unsigned short* wkb = (unsigned short*)(ws + 8 * MB);
  unsigned short* wvb = (unsigned short*)(ws + 16 * MB);
  unsigned short* wob = (unsigned short*)(ws + 24 * MB);
  unsigned short* xb  = (unsigned short*)(ws + 32 * MB);
  unsigned short* Qb  = (unsigned short*)(ws + 64 * MB);
  unsigned short* Kb  = (unsigned short*)(ws + 96 * MB);
  unsigned short* Vtb = (unsigned short*)(ws + 128 * MB);
  unsigned short* Yb  = xb;  // reuse x's bf16 buffer after QKV GEMMs

  cvt_all<<<32768, 256, 0, stream>>>(x, wq, wk, wv, wo, xb, wqb, wkb, wvb, wob);

  gemm_qkv<<<dim3(HM / 256, 24), 512, 0, stream>>>(xb, wqb, wkb, wvb, Qb, Kb, Vtb);

  attn_kernel<<<2048, 256, 0, stream>>>(Qb, Kb, Vtb, Yb);

  gemm_out<<<dim3(HM / 256, HC / 256), 512, 0, stream>>>(Yb, wob, out);
}

// Round 2
// 545.944 us; speedup vs baseline: 1.0502x; 1.0502x over previous
//
#include <hip/hip_runtime.h>

#define HB 32
#define HT 256
#define HC 2048
#define HH 16
#define HD 128
#define HM (HB * HT)  // 8192

typedef __bf16 bf16x8 __attribute__((ext_vector_type(8)));
typedef float f32x4 __attribute__((ext_vector_type(4)));

__device__ __forceinline__ unsigned short f2bf(float f) {
  unsigned u = __float_as_uint(f);
  u += 0x7FFFu + ((u >> 16) & 1u);  // round-to-nearest-even
  return (unsigned short)(u >> 16);
}

// ---------------- fused fp32 -> bf16 convert (x + 4 weights) ----------------
__global__ __launch_bounds__(256) void cvt_all(
    const float* __restrict__ x, const float* __restrict__ wq, const float* __restrict__ wk,
    const float* __restrict__ wv, const float* __restrict__ wo,
    unsigned short* __restrict__ xb, unsigned short* __restrict__ wqb,
    unsigned short* __restrict__ wkb, unsigned short* __restrict__ wvb,
    unsigned short* __restrict__ wob) {
  size_t i = (size_t)blockIdx.x * 256 + threadIdx.x;
  const float* src;
  unsigned short* dst;
  size_t off;
  if (i < 4194304) {
    src = x; dst = xb; off = i;
  } else {
    size_t j = i - 4194304;
    int w = (int)(j >> 20);
    off = j & 1048575;
    src = (w == 0) ? wq : (w == 1) ? wk : (w == 2) ? wv : wo;
    dst = (w == 0) ? wqb : (w == 1) ? wkb : (w == 2) ? wvb : wob;
  }
  float4 v = ((const float4*)src)[off];
  ushort4 o;
  o.x = f2bf(v.x); o.y = f2bf(v.y); o.z = f2bf(v.z); o.w = f2bf(v.w);
  ((ushort4*)dst)[off] = o;
}

// ---------------- GEMM core: 256x256 tile, BK=32, 4-deep ring, 2 phases/tile ----
// Faithful 8-phase-template port (m194-m201): per phase = {8 ds_read_b128 ||
// 2 global_load_lds issue || [counted vmcnt once/tile] -> barrier -> setprio(1)
// -> 16 MFMA -> setprio(0) -> barrier}. Prefetch distance 3 tiles => steady-state
// wait is vmcnt(8) for loads issued 4 phases earlier; never drains to 0 until the
// 2-tile tail. Swizzle chunk^= (row&3) verified 0-conflict in round 1.
__device__ __forceinline__ void gl_lds16(const unsigned short* g, unsigned short* l) {
  __builtin_amdgcn_global_load_lds((const __attribute__((address_space(1))) void*)g,
                                   (__attribute__((address_space(3))) void*)l, 16, 0, 0);
}

// wave wn owns col-blocks {h*128 + s, +16, +64+s, +80} with s=32*(wn&1), h=wn>>1:
// frag pair (nf, nf+2) is (d, d+64) of one head -> RoPE pair stays in-lane.
__device__ __forceinline__ int nfcol(int wn, int nf) {
  return (wn >> 1) * 128 + (wn & 1) * 32 + (nf & 1) * 16 + (nf >> 1) * 64;
}

// Stage one 256x32 bf16 tile (16 KB) = 2 x 16B loads/thread. LDS dest linear
// (chunk c at byte c*16, wave-uniform base + lane*16); source column pre-swizzled
// gc = slot ^ (row&3) (m173 both-sides pattern).
__device__ __forceinline__ void stage32(const unsigned short* __restrict__ src,
                                        unsigned short* dst, int tid) {
#pragma unroll
  for (int i = 0; i < 2; i++) {
    int c = i * 512 + tid;
    int row = c >> 2, slot = c & 3;
    int gc = slot ^ (row & 3);
    gl_lds16(src + (size_t)row * HC + gc * 8, dst + c * 8);
  }
}

#define KT 64  // K=2048 / BK=32

__device__ __forceinline__ void gemm_core8(const unsigned short* __restrict__ A,
                                           const unsigned short* __restrict__ W,
                                           unsigned short* lsA, unsigned short* lsB,
                                           f32x4 acc[8][4], int tid) {
  const int lane = tid & 63, l16 = lane & 15, quad = lane >> 4;
  const int wave = tid >> 6, wm = wave >> 2, wn = wave & 3;

  // prologue: stage tiles 0,1,2 (12 loads); vmcnt(8) -> tile 0 landed, 1-2 in flight
  stage32(A, lsA, tid);
  stage32(W, lsB, tid);
  stage32(A + 32, lsA + 8192, tid);
  stage32(W + 32, lsB + 8192, tid);
  stage32(A + 64, lsA + 16384, tid);
  stage32(W + 64, lsB + 16384, tid);
  asm volatile("s_waitcnt vmcnt(8)");
  __builtin_amdgcn_s_barrier();

  for (int t = 0; t < KT; ++t) {
    const unsigned short* cA = lsA + (t & 3) * 8192;
    const unsigned short* cB = lsB + (t & 3) * 8192;
    unsigned short* nA = lsA + ((t + 3) & 3) * 8192;  // buffer of t-1: freed at its ph1 barrier-2
    unsigned short* nB = lsB + ((t + 3) & 3) * 8192;
    const bool pf = (t + 3 < KT);
#pragma unroll
    for (int ph = 0; ph < 2; ++ph) {
      // --- 8 x ds_read_b128: one output quadrant's fragments (issued early,
      //     latency overlaps barrier + MFMA ramp; compiler emits fine lgkmcnt) ---
      bf16x8 af[4], bfv[4];
#pragma unroll
      for (int mf = 0; mf < 4; ++mf) {
        int row = wm * 128 + ph * 64 + mf * 16 + l16;
        int ch = quad ^ (row & 3);
        af[mf] = *(const bf16x8*)(cA + row * 32 + ch * 8);
      }
#pragma unroll
      for (int nf = 0; nf < 4; ++nf) {
        int row = nfcol(wn, nf) + l16;
        int ch = quad ^ (row & 3);
        bfv[nf] = *(const bf16x8*)(cB + row * 32 + ch * 8);
      }
      // --- issue 1 half-tile prefetch for tile t+3 ---
      if (pf) {
        if (ph == 0) stage32(A + (size_t)(t + 3) * 32, nA, tid);
        else         stage32(W + (size_t)(t + 3) * 32, nB, tid);
      }
      // --- counted vmcnt once per K-tile, BEFORE a barrier (publishes tile t+1
      //     cross-wave). Steady state: retires t+1's 4 loads, keeps t+2,t+3 (8)
      //     in flight. Tail drains 8 -> 4 -> 0. ---
      if (ph == 1) {
        const int rem = KT - 2 - t;
        if (rem >= 2)      asm volatile("s_waitcnt vmcnt(8)");
        else if (rem == 1) asm volatile("s_waitcnt vmcnt(4)");
        else if (rem == 0) asm volatile("s_waitcnt vmcnt(0)");
      }
      __builtin_amdgcn_s_barrier();
      __builtin_amdgcn_s_setprio(1);
#pragma unroll
      for (int mf = 0; mf < 4; ++mf)
#pragma unroll
        for (int nf = 0; nf < 4; ++nf)
          acc[ph * 4 + mf][nf] =
              __builtin_amdgcn_mfma_f32_16x16x32_bf16(af[mf], bfv[nf], acc[ph * 4 + mf][nf], 0, 0, 0);
      __builtin_amdgcn_s_setprio(0);
      __builtin_amdgcn_s_barrier();
    }
  }
}

// Output projection GEMM: fp32 out [M, 2048]; grid (32, 8)
__global__ __launch_bounds__(512, 2) void gemm_out(const unsigned short* __restrict__ A,
                                                   const unsigned short* __restrict__ W,
                                                   float* __restrict__ outp) {
  __shared__ __align__(16) unsigned short lsA[32768];
  __shared__ __align__(16) unsigned short lsB[32768];
  const int tid = threadIdx.x;
  const int lane = tid & 63, wave = tid >> 6;
  const int l16 = lane & 15, quad = lane >> 4;
  const int wm = wave >> 2, wn = wave & 3;
  const int bm = blockIdx.x, bn = blockIdx.y;

  f32x4 acc[8][4];
#pragma unroll
  for (int i = 0; i < 8; i++)
#pragma unroll
    for (int j = 0; j < 4; j++) acc[i][j] = f32x4{0.f, 0.f, 0.f, 0.f};

  gemm_core8(A + (size_t)bm * 256 * HC, W + (size_t)bn * 256 * HC, lsA, lsB, acc, tid);

#pragma unroll
  for (int mf = 0; mf < 8; mf++)
#pragma unroll
    for (int nf = 0; nf < 4; nf++) {
      const int n = bn * 256 + nfcol(wn, nf) + l16;
#pragma unroll
      for (int r = 0; r < 4; r++) {
        const int m = bm * 256 + wm * 128 + mf * 16 + quad * 4 + r;
        outp[(size_t)m * HC + n] = acc[mf][nf][r];
      }
    }
}

// Fused QKV GEMM: grid (32, 24); blockIdx.y>>3 selects {Q,K,V}.
// Q,K -> [B,H,T,D] with RoPE fused; V -> [B,H,D,T] via operand swap (coalesced).
__global__ __launch_bounds__(512, 2) void gemm_qkv(const unsigned short* __restrict__ A,
                                                   const unsigned short* __restrict__ W0,
                                                   const unsigned short* __restrict__ W1,
                                                   const unsigned short* __restrict__ W2,
                                                   unsigned short* __restrict__ Qo,
                                                   unsigned short* __restrict__ Ko,
                                                   unsigned short* __restrict__ Vto) {
  __shared__ __align__(16) unsigned short lsA[32768];
  __shared__ __align__(16) unsigned short lsB[32768];
  const int tid = threadIdx.x;
  const int lane = tid & 63, wave = tid >> 6;
  const int l16 = lane & 15, quad = lane >> 4;
  const int wm = wave >> 2, wn = wave & 3;
  const int bm = blockIdx.x;
  const int which = blockIdx.y >> 3;
  const int bn = blockIdx.y & 7;

  f32x4 acc[8][4];
#pragma unroll
  for (int i = 0; i < 8; i++)
#pragma unroll
    for (int j = 0; j < 4; j++) acc[i][j] = f32x4{0.f, 0.f, 0.f, 0.f};

  if (which < 2) {
    const unsigned short* W = (which == 0) ? W0 : W1;
    unsigned short* outp = (which == 0) ? Qo : Ko;
    gemm_core8(A + (size_t)bm * 256 * HC, W + (size_t)bn * 256 * HC, lsA, lsB, acc, tid);
    // wave covers head h = bn*2 + (wn>>1); frag pair (p, p+2) = (d, d+64) in-lane.
    const int h = bn * 2 + (wn >> 1);
#pragma unroll
    for (int p = 0; p < 2; p++) {
      const int d = (wn & 1) * 32 + p * 16 + l16;  // [0,64)
      const float invf = __expf((float)d * (-0.14391156831212787f));
#pragma unroll
      for (int mf = 0; mf < 8; mf++)
#pragma unroll
        for (int r = 0; r < 4; r++) {
          const int m = bm * 256 + wm * 128 + mf * 16 + quad * 4 + r;
          const int t = m & 255, b = m >> 8;
          float ang = (float)t * invf;
          float sn, cs;
          __sincosf(ang, &sn, &cs);
          float lo = acc[mf][p][r], hi = acc[mf][p + 2][r];
          size_t base = (((size_t)b * HH + h) * HT + t) * HD;
          outp[base + d] = f2bf(lo * cs - hi * sn);
          outp[base + 64 + d] = f2bf(hi * cs + lo * sn);
        }
    }
  } else {
    // V^T: A-operand = wv channel tile (256 ch = 2 heads), B-operand = x token tile (256 = 1 batch).
    const int tok = bm;  // 0..31
    const int ch = bn;   // 0..7
    gemm_core8(W2 + (size_t)ch * 256 * HC, A + (size_t)tok * 256 * HC, lsA, lsB, acc, tid);
#pragma unroll
    for (int mf = 0; mf < 8; mf++)
#pragma unroll
      for (int nf = 0; nf < 4; nf++) {
        const int tcol = nfcol(wn, nf) + l16;
#pragma unroll
        for (int r = 0; r < 4; r++) {
          const int cabs = ch * 256 + wm * 128 + mf * 16 + quad * 4 + r;
          const int hh = cabs >> 7, d = cabs & 127;
          Vto[(((size_t)tok * HH + hh) * HD + d) * HT + tcol] = f2bf(acc[mf][nf][r]);
        }
      }
  }
}

// ---------------- causal flash attention ----------------
// Block = 4 waves; block handles 64 q-rows of one (b,h); wave owns 16 q-rows.
// Q,K in [B,H,T,D] (pre-RoPEd), Vt in [B,H,D,T]. Y written as [B,T,C] bf16.
__global__ __launch_bounds__(256) void attn_kernel(const unsigned short* __restrict__ Q,
                                                   const unsigned short* __restrict__ K,
                                                   const unsigned short* __restrict__ Vt,
                                                   unsigned short* __restrict__ Y) {
  const int g = blockIdx.x;
  const int wq = 3 - (g >> 9);
  const int bh = g & 511;
  const int wave = threadIdx.x >> 6;
  const int lane = threadIdx.x & 63;
  const int quad = lane >> 4, l16 = lane & 15;

  const unsigned short* Qh = Q + (size_t)bh * HT * HD;
  const unsigned short* Kh = K + (size_t)bh * HT * HD;
  const unsigned short* Vh = Vt + (size_t)bh * HD * HT;

  __shared__ __align__(16) unsigned short P[4][16 * 72];
  unsigned short* Pw = P[wave];

  const int qrow = wq * 64 + wave * 16;

  bf16x8 qf[4];
#pragma unroll
  for (int ks = 0; ks < 4; ks++)
    qf[ks] = *(const bf16x8*)(Qh + (size_t)(qrow + l16) * HD + ks * 32 + quad * 8);

  f32x4 o[8];
#pragma unroll
  for (int di = 0; di < 8; di++) o[di] = f32x4{0.f, 0.f, 0.f, 0.f};
  float mrow[4], lrow[4];
#pragma unroll
  for (int r = 0; r < 4; r++) { mrow[r] = -1e30f; lrow[r] = 0.f; }

  const float scale = 0.088388347648318447f;  // 1/sqrt(128)

  for (int ct = 0; ct <= wq; ++ct) {
    f32x4 s[4];
#pragma unroll
    for (int ni = 0; ni < 4; ni++) s[ni] = f32x4{0.f, 0.f, 0.f, 0.f};
    const int nimax = (ct == wq) ? wave : 3;
#pragma unroll
    for (int ks = 0; ks < 4; ks++) {
#pragma unroll
      for (int ni = 0; ni < 4; ni++) {
        if (ni <= nimax) {
          bf16x8 kf = *(const bf16x8*)(Kh + (size_t)(ct * 64 + ni * 16 + l16) * HD + ks * 32 + quad * 8);
          s[ni] = __builtin_amdgcn_mfma_f32_16x16x32_bf16(qf[ks], kf, s[ni], 0, 0, 0);
        }
      }
    }
    if (ct == wq) {
#pragma unroll
      for (int ni = 0; ni < 4; ni++)
#pragma unroll
        for (int r = 0; r < 4; r++) {
          int qr = wave * 16 + quad * 4 + r;
          int kc = ni * 16 + l16;
          s[ni][r] = (kc <= qr) ? s[ni][r] * scale : -1e30f;
        }
    } else {
#pragma unroll
      for (int ni = 0; ni < 4; ni++)
#pragma unroll
        for (int r = 0; r < 4; r++) s[ni][r] *= scale;
    }
#pragma unroll
    for (int r = 0; r < 4; r++) {
      float v = fmaxf(fmaxf(s[0][r], s[1][r]), fmaxf(s[2][r], s[3][r]));
      v = fmaxf(v, __shfl_xor(v, 1, 64));
      v = fmaxf(v, __shfl_xor(v, 2, 64));
      v = fmaxf(v, __shfl_xor(v, 4, 64));
      v = fmaxf(v, __shfl_xor(v, 8, 64));
      float mnew = fmaxf(mrow[r], v);
      float alpha = __expf(mrow[r] - mnew);
      mrow[r] = mnew;
      float rs = 0.f;
#pragma unroll
      for (int ni = 0; ni < 4; ni++) {
        float e = __expf(s[ni][r] - mnew);
        s[ni][r] = e;
        rs += e;
      }
      rs += __shfl_xor(rs, 1, 64);
      rs += __shfl_xor(rs, 2, 64);
      rs += __shfl_xor(rs, 4, 64);
      rs += __shfl_xor(rs, 8, 64);
      lrow[r] = lrow[r] * alpha + rs;
#pragma unroll
      for (int di = 0; di < 8; di++) o[di][r] *= alpha;
    }
#pragma unroll
    for (int ni = 0; ni < 4; ni++)
#pragma unroll
      for (int r = 0; r < 4; r++)
        Pw[(quad * 4 + r) * 72 + ni * 16 + l16] = f2bf(s[ni][r]);
#pragma unroll
    for (int ks = 0; ks < 2; ks++) {
      bf16x8 pf = *(const bf16x8*)(Pw + (size_t)l16 * 72 + ks * 32 + quad * 8);
#pragma unroll
      for (int di = 0; di < 8; di++) {
        bf16x8 vf = *(const bf16x8*)(Vh + (size_t)(di * 16 + l16) * HT + ct * 64 + ks * 32 + quad * 8);
        o[di] = __builtin_amdgcn_mfma_f32_16x16x32_bf16(pf, vf, o[di], 0, 0, 0);
      }
    }
  }

  const int b = bh >> 4, h = bh & 15;
#pragma unroll
  for (int r = 0; r < 4; r++) {
    float inv = 1.f / lrow[r];
    int t = qrow + quad * 4 + r;
    size_t rowb = ((size_t)b * HT + t) * HC + h * HD;
#pragma unroll
    for (int di = 0; di < 8; di++)
      Y[rowb + di * 16 + l16] = f2bf(o[di][r] * inv);
  }
}

// ---------------- launch ----------------
extern "C" void kernel_launch(void* const* d_in, const int* in_sizes, int n_in,
                              void* d_out, int out_size, void* d_ws, size_t ws_size,
                              hipStream_t stream) {
  const float* x  = (const float*)d_in[0];
  const float* wq = (const float*)d_in[1];
  const float* wk = (const float*)d_in[2];
  const float* wv = (const float*)d_in[3];
  const float* wo = (const float*)d_in[4];
  float* out = (float*)d_out;

  char* ws = (char*)d_ws;
  const size_t MB = (size_t)1 << 20;
  unsigned short* wqb = (unsigned short*)(ws + 0 * MB);
  unsigned short* wkb = (unsigned short*)(ws + 8 * MB);
  unsigned short* wvb = (unsigned short*)(ws + 16 * MB);
  unsigned short* wob = (unsigned short*)(ws + 24 * MB);
  unsigned short* xb  = (unsigned short*)(ws + 32 * MB);
  unsigned short* Qb  = (unsigned short*)(ws + 64 * MB);
  unsigned short* Kb  = (unsigned short*)(ws + 96 * MB);
  unsigned short* Vtb = (unsigned short*)(ws + 128 * MB);
  unsigned short* Yb  = xb;  // reuse x's bf16 buffer after QKV GEMMs

  cvt_all<<<32768, 256, 0, stream>>>(x, wq, wk, wv, wo, xb, wqb, wkb, wvb, wob);

  gemm_qkv<<<dim3(HM / 256, 24), 512, 0, stream>>>(xb, wqb, wkb, wvb, Qb, Kb, Vtb);

  attn_kernel<<<2048, 256, 0, stream>>>(Qb, Kb, Vtb, Yb);

  gemm_out<<<dim3(HM / 256, HC / 256), 512, 0, stream>>>(Yb, wob, out);
}

// Round 3
// 496.961 us; speedup vs baseline: 1.1537x; 1.0986x over previous
//
#include <hip/hip_runtime.h>

#define HB 32
#define HT 256
#define HC 2048
#define HH 16
#define HD 128
#define HM (HB * HT)  // 8192

typedef __bf16 bf16x8 __attribute__((ext_vector_type(8)));
typedef float f32x4 __attribute__((ext_vector_type(4)));

__device__ __forceinline__ unsigned short f2bf(float f) {
  unsigned u = __float_as_uint(f);
  u += 0x7FFFu + ((u >> 16) & 1u);  // round-to-nearest-even
  return (unsigned short)(u >> 16);
}

// ---------------- fused fp32 -> bf16 convert (x + 4 weights) ----------------
__global__ __launch_bounds__(256) void cvt_all(
    const float* __restrict__ x, const float* __restrict__ wq, const float* __restrict__ wk,
    const float* __restrict__ wv, const float* __restrict__ wo,
    unsigned short* __restrict__ xb, unsigned short* __restrict__ wqb,
    unsigned short* __restrict__ wkb, unsigned short* __restrict__ wvb,
    unsigned short* __restrict__ wob) {
  size_t i = (size_t)blockIdx.x * 256 + threadIdx.x;
  const float* src;
  unsigned short* dst;
  size_t off;
  if (i < 4194304) {
    src = x; dst = xb; off = i;
  } else {
    size_t j = i - 4194304;
    int w = (int)(j >> 20);
    off = j & 1048575;
    src = (w == 0) ? wq : (w == 1) ? wk : (w == 2) ? wv : wo;
    dst = (w == 0) ? wqb : (w == 1) ? wkb : (w == 2) ? wvb : wob;
  }
  float4 v = ((const float4*)src)[off];
  ushort4 o;
  o.x = f2bf(v.x); o.y = f2bf(v.y); o.z = f2bf(v.z); o.w = f2bf(v.w);
  ((ushort4*)dst)[off] = o;
}

// ---------------- GEMM core: 128x256 block tile, BK=64, 16x16x32 MFMA ----------------
// Round-0 block structure (4 waves, 48 KiB, stage-all -> barrier -> compute,
// 2-3 blocks/CU inter-block overlap) with the conflict-free LDS config proven in
// round 1: tiles stored as two [rows][32] k-half planes (64B row pitch), fragment
// reads are 16 consecutive rows x quad-chunk, chunk = quad ^ ((l16>>1)&3).
// Round-1 measured SQ_LDS_BANK_CONFLICT = 0 for exactly this pattern; round-0's
// 128B-pitch/32-row pattern measured 1.89e7 (a ~4-way tax on a near-saturated
// LDS pipe). Intensity stays 42.7 FLOP/LDS-byte (24 b128 reads, 1.05 MFLOP /kt/wave).
__device__ __forceinline__ void gl_lds16(const unsigned short* g, unsigned short* l) {
  __builtin_amdgcn_global_load_lds((const __attribute__((address_space(1))) void*)g,
                                   (__attribute__((address_space(3))) void*)l, 16, 0, 0);
}

// Per wave: 64x128 output = acc[4 m-frags][8 n-frags], 16x16x32 MFMA.
// C-layout (m89-verified): row = quad*4 + reg, col = l16.
__device__ __forceinline__ void gemm_core_wide(const unsigned short* __restrict__ Ab,
                                               const unsigned short* __restrict__ Wb,
                                               unsigned short* lsA, unsigned short* lsB,
                                               f32x4 acc[4][8], int tid) {
  const int lane = tid & 63, wave = tid >> 6;
  const int l16 = lane & 15, quad = lane >> 4;
  const int wr = wave >> 1, wc = wave & 1;
  // swizzle is row-independent at 16-aligned fragment rows: bits 1-2 of row == bits 1-2 of l16
  const int ch = (quad ^ ((l16 >> 1) & 3)) * 8;

  for (int kt = 0; kt < HC / 64; ++kt) {
    __syncthreads();
    // stage A: [2 kh][128 rows][32] = 1024 x 16B chunks; vrow = kh*128 + row
#pragma unroll
    for (int i = 0; i < 4; i++) {
      int c = i * 256 + tid;
      int vrow = c >> 2, slot = c & 3;
      int gc = slot ^ ((vrow >> 1) & 3);
      int row = vrow & 127, kh = vrow >> 7;
      gl_lds16(Ab + (size_t)row * HC + kt * 64 + kh * 32 + gc * 8, lsA + c * 8);
    }
    // stage B: [2 kh][256 rows][32] = 2048 chunks
#pragma unroll
    for (int i = 0; i < 8; i++) {
      int c = i * 256 + tid;
      int vrow = c >> 2, slot = c & 3;
      int gc = slot ^ ((vrow >> 1) & 3);
      int row = vrow & 255, kh = vrow >> 8;
      gl_lds16(Wb + (size_t)row * HC + kt * 64 + kh * 32 + gc * 8, lsB + c * 8);
    }
    __syncthreads();
#pragma unroll
    for (int kh = 0; kh < 2; ++kh) {
      bf16x8 af[4], bfr[8];
#pragma unroll
      for (int mi = 0; mi < 4; mi++) {
        int r = wr * 64 + mi * 16 + l16;
        af[mi] = *(const bf16x8*)(lsA + (kh * 128 + r) * 32 + ch);
      }
#pragma unroll
      for (int nj = 0; nj < 8; nj++) {
        int r = wc * 128 + nj * 16 + l16;
        bfr[nj] = *(const bf16x8*)(lsB + (kh * 256 + r) * 32 + ch);
      }
#pragma unroll
      for (int mi = 0; mi < 4; mi++)
#pragma unroll
        for (int nj = 0; nj < 8; nj++)
          acc[mi][nj] = __builtin_amdgcn_mfma_f32_16x16x32_bf16(af[mi], bfr[nj], acc[mi][nj], 0, 0, 0);
    }
  }
}

// Output projection GEMM: fp32 out [M, 2048]; grid (64, 8)
__global__ __launch_bounds__(256, 2) void gemm_out(const unsigned short* __restrict__ A,
                                                   const unsigned short* __restrict__ W,
                                                   float* __restrict__ outp) {
  __shared__ __align__(16) unsigned short lsA[2 * 128 * 32];
  __shared__ __align__(16) unsigned short lsB[2 * 256 * 32];
  const int tid = threadIdx.x;
  const int lane = tid & 63, wave = tid >> 6;
  const int l16 = lane & 15, quad = lane >> 4;
  const int wr = wave >> 1, wc = wave & 1;
  const int bm = blockIdx.x, bn = blockIdx.y;

  f32x4 acc[4][8];
#pragma unroll
  for (int i = 0; i < 4; i++)
#pragma unroll
    for (int j = 0; j < 8; j++) acc[i][j] = f32x4{0.f, 0.f, 0.f, 0.f};

  gemm_core_wide(A + (size_t)bm * 128 * HC, W + (size_t)bn * 256 * HC, lsA, lsB, acc, tid);

#pragma unroll
  for (int mi = 0; mi < 4; mi++)
#pragma unroll
    for (int nj = 0; nj < 8; nj++) {
      const int n = bn * 256 + wc * 128 + nj * 16 + l16;
#pragma unroll
      for (int rr = 0; rr < 4; rr++) {
        const int m = bm * 128 + wr * 64 + mi * 16 + quad * 4 + rr;
        outp[(size_t)m * HC + n] = acc[mi][nj][rr];
      }
    }
}

// Fused QKV GEMM: grid (64, 24); blockIdx.y>>3 selects {Q,K,V}.
// Q,K -> [B,H,T,D] with RoPE fused; V -> [B,H,D,T] via operand swap (coalesced).
__global__ __launch_bounds__(256, 2) void gemm_qkv(const unsigned short* __restrict__ A,
                                                    const unsigned short* __restrict__ W0,
                                                    const unsigned short* __restrict__ W1,
                                                    const unsigned short* __restrict__ W2,
                                                    unsigned short* __restrict__ Qo,
                                                    unsigned short* __restrict__ Ko,
                                                    unsigned short* __restrict__ Vto) {
  __shared__ __align__(16) unsigned short lsA[2 * 128 * 32];
  __shared__ __align__(16) unsigned short lsB[2 * 256 * 32];
  const int tid = threadIdx.x;
  const int lane = tid & 63, wave = tid >> 6;
  const int l16 = lane & 15, quad = lane >> 4;
  const int wr = wave >> 1, wc = wave & 1;
  const int bm = blockIdx.x;
  const int which = blockIdx.y >> 3;
  const int bn = blockIdx.y & 7;

  f32x4 acc[4][8];
#pragma unroll
  for (int i = 0; i < 4; i++)
#pragma unroll
    for (int j = 0; j < 8; j++) acc[i][j] = f32x4{0.f, 0.f, 0.f, 0.f};

  if (which < 2) {
    const unsigned short* W = (which == 0) ? W0 : W1;
    unsigned short* outp = (which == 0) ? Qo : Ko;
    gemm_core_wide(A + (size_t)bm * 128 * HC, W + (size_t)bn * 256 * HC, lsA, lsB, acc, tid);
    // Wave's 128 cols = one head: h = bn*2 + wc. RoPE pair: acc[mi][nj] (d) with
    // acc[mi][nj+4] (d+64), d = nj*16 + l16, nj in {0..3}.
    const int h = bn * 2 + wc;
#pragma unroll
    for (int nj = 0; nj < 4; nj++) {
      const int dlo = nj * 16 + l16;
      const float invf = __expf((float)dlo * (-0.14391156831212787f));
#pragma unroll
      for (int mi = 0; mi < 4; mi++)
#pragma unroll
        for (int rr = 0; rr < 4; rr++) {
          const int m = bm * 128 + wr * 64 + mi * 16 + quad * 4 + rr;
          const int t = m & 255, b = m >> 8;
          float ang = (float)t * invf;
          float sn, cs;
          __sincosf(ang, &sn, &cs);
          float lo = acc[mi][nj][rr], hi = acc[mi][nj + 4][rr];
          size_t base = (((size_t)b * HH + h) * HT + t) * HD;
          outp[base + dlo] = f2bf(lo * cs - hi * sn);
          outp[base + 64 + dlo] = f2bf(hi * cs + lo * sn);
        }
    }
  } else {
    // V^T: A-operand = wv channel tile (128 ch = one head), B-operand = x token tile (256).
    int v = bn * 64 + bm;            // 512 blocks
    int tok = v & 31, ch2 = v >> 5;  // 32 token-tiles x 16 channel-tiles
    gemm_core_wide(W2 + (size_t)ch2 * 128 * HC, A + (size_t)tok * 256 * HC, lsA, lsB, acc, tid);
    const int b = tok, h = ch2;
#pragma unroll
    for (int mi = 0; mi < 4; mi++)
#pragma unroll
      for (int nj = 0; nj < 8; nj++) {
        const int t = wc * 128 + nj * 16 + l16;
#pragma unroll
        for (int rr = 0; rr < 4; rr++) {
          const int d = wr * 64 + mi * 16 + quad * 4 + rr;
          Vto[(((size_t)b * HH + h) * HD + d) * HT + t] = f2bf(acc[mi][nj][rr]);
        }
      }
  }
}

// ---------------- causal flash attention ----------------
// Block = 4 waves; block handles 64 q-rows of one (b,h); wave owns 16 q-rows.
// Q,K in [B,H,T,D] (pre-RoPEd), Vt in [B,H,D,T]. Y written as [B,T,C] bf16.
__global__ __launch_bounds__(256) void attn_kernel(const unsigned short* __restrict__ Q,
                                                   const unsigned short* __restrict__ K,
                                                   const unsigned short* __restrict__ Vt,
                                                   unsigned short* __restrict__ Y) {
  const int g = blockIdx.x;
  const int wq = 3 - (g >> 9);
  const int bh = g & 511;
  const int wave = threadIdx.x >> 6;
  const int lane = threadIdx.x & 63;
  const int quad = lane >> 4, l16 = lane & 15;

  const unsigned short* Qh = Q + (size_t)bh * HT * HD;
  const unsigned short* Kh = K + (size_t)bh * HT * HD;
  const unsigned short* Vh = Vt + (size_t)bh * HD * HT;

  __shared__ __align__(16) unsigned short P[4][16 * 72];
  unsigned short* Pw = P[wave];

  const int qrow = wq * 64 + wave * 16;

  bf16x8 qf[4];
#pragma unroll
  for (int ks = 0; ks < 4; ks++)
    qf[ks] = *(const bf16x8*)(Qh + (size_t)(qrow + l16) * HD + ks * 32 + quad * 8);

  f32x4 o[8];
#pragma unroll
  for (int di = 0; di < 8; di++) o[di] = f32x4{0.f, 0.f, 0.f, 0.f};
  float mrow[4], lrow[4];
#pragma unroll
  for (int r = 0; r < 4; r++) { mrow[r] = -1e30f; lrow[r] = 0.f; }

  const float scale = 0.088388347648318447f;  // 1/sqrt(128)

  for (int ct = 0; ct <= wq; ++ct) {
    f32x4 s[4];
#pragma unroll
    for (int ni = 0; ni < 4; ni++) s[ni] = f32x4{0.f, 0.f, 0.f, 0.f};
    const int nimax = (ct == wq) ? wave : 3;
#pragma unroll
    for (int ks = 0; ks < 4; ks++) {
#pragma unroll
      for (int ni = 0; ni < 4; ni++) {
        if (ni <= nimax) {
          bf16x8 kf = *(const bf16x8*)(Kh + (size_t)(ct * 64 + ni * 16 + l16) * HD + ks * 32 + quad * 8);
          s[ni] = __builtin_amdgcn_mfma_f32_16x16x32_bf16(qf[ks], kf, s[ni], 0, 0, 0);
        }
      }
    }
    if (ct == wq) {
#pragma unroll
      for (int ni = 0; ni < 4; ni++)
#pragma unroll
        for (int r = 0; r < 4; r++) {
          int qr = wave * 16 + quad * 4 + r;
          int kc = ni * 16 + l16;
          s[ni][r] = (kc <= qr) ? s[ni][r] * scale : -1e30f;
        }
    } else {
#pragma unroll
      for (int ni = 0; ni < 4; ni++)
#pragma unroll
        for (int r = 0; r < 4; r++) s[ni][r] *= scale;
    }
#pragma unroll
    for (int r = 0; r < 4; r++) {
      float v = fmaxf(fmaxf(s[0][r], s[1][r]), fmaxf(s[2][r], s[3][r]));
      v = fmaxf(v, __shfl_xor(v, 1, 64));
      v = fmaxf(v, __shfl_xor(v, 2, 64));
      v = fmaxf(v, __shfl_xor(v, 4, 64));
      v = fmaxf(v, __shfl_xor(v, 8, 64));
      float mnew = fmaxf(mrow[r], v);
      float alpha = __expf(mrow[r] - mnew);
      mrow[r] = mnew;
      float rs = 0.f;
#pragma unroll
      for (int ni = 0; ni < 4; ni++) {
        float e = __expf(s[ni][r] - mnew);
        s[ni][r] = e;
        rs += e;
      }
      rs += __shfl_xor(rs, 1, 64);
      rs += __shfl_xor(rs, 2, 64);
      rs += __shfl_xor(rs, 4, 64);
      rs += __shfl_xor(rs, 8, 64);
      lrow[r] = lrow[r] * alpha + rs;
#pragma unroll
      for (int di = 0; di < 8; di++) o[di][r] *= alpha;
    }
#pragma unroll
    for (int ni = 0; ni < 4; ni++)
#pragma unroll
      for (int r = 0; r < 4; r++)
        Pw[(quad * 4 + r) * 72 + ni * 16 + l16] = f2bf(s[ni][r]);
#pragma unroll
    for (int ks = 0; ks < 2; ks++) {
      bf16x8 pf = *(const bf16x8*)(Pw + (size_t)l16 * 72 + ks * 32 + quad * 8);
#pragma unroll
      for (int di = 0; di < 8; di++) {
        bf16x8 vf = *(const bf16x8*)(Vh + (size_t)(di * 16 + l16) * HT + ct * 64 + ks * 32 + quad * 8);
        o[di] = __builtin_amdgcn_mfma_f32_16x16x32_bf16(pf, vf, o[di], 0, 0, 0);
      }
    }
  }

  const int b = bh >> 4, h = bh & 15;
#pragma unroll
  for (int r = 0; r < 4; r++) {
    float inv = 1.f / lrow[r];
    int t = qrow + quad * 4 + r;
    size_t rowb = ((size_t)b * HT + t) * HC + h * HD;
#pragma unroll
    for (int di = 0; di < 8; di++)
      Y[rowb + di * 16 + l16] = f2bf(o[di][r] * inv);
  }
}

// ---------------- launch ----------------
extern "C" void kernel_launch(void* const* d_in, const int* in_sizes, int n_in,
                              void* d_out, int out_size, void* d_ws, size_t ws_size,
                              hipStream_t stream) {
  const float* x  = (const float*)d_in[0];
  const float* wq = (const float*)d_in[1];
  const float* wk = (const float*)d_in[2];
  const float* wv = (const float*)d_in[3];
  const float* wo = (const float*)d_in[4];
  float* out = (float*)d_out;

  char* ws = (char*)d_ws;
  const size_t MB = (size_t)1 << 20;
  unsigned short* wqb = (unsigned short*)(ws + 0 * MB);
  unsigned short* wkb = (unsigned short*)(ws + 8 * MB);
  unsigned short* wvb = (unsigned short*)(ws + 16 * MB);
  unsigned short* wob = (unsigned short*)(ws + 24 * MB);
  unsigned short* xb  = (unsigned short*)(ws + 32 * MB);
  unsigned short* Qb  = (unsigned short*)(ws + 64 * MB);
  unsigned short* Kb  = (unsigned short*)(ws + 96 * MB);
  unsigned short* Vtb = (unsigned short*)(ws + 128 * MB);
  unsigned short* Yb  = xb;  // reuse x's bf16 buffer after QKV GEMMs

  cvt_all<<<32768, 256, 0, stream>>>(x, wq, wk, wv, wo, xb, wqb, wkb, wvb, wob);

  gemm_qkv<<<dim3(HM / 128, 24), 256, 0, stream>>>(xb, wqb, wkb, wvb, Qb, Kb, Vtb);

  attn_kernel<<<2048, 256, 0, stream>>>(Qb, Kb, Vtb, Yb);

  gemm_out<<<dim3(HM / 128, HC / 256), 256, 0, stream>>>(Yb, wob, out);
}